// Round 22
// baseline (44.789 us; speedup 1.0000x reference)
//
#include <hip/hip_runtime.h>
#include <math.h>

#define PSTR 33   // part[] col stride: 33 mod 32 = 1 -> benign 2-way bank aliasing

// ======== compile-time gaussian (sigma=65/sqrt(2), normalized over 65) ========
constexpr double cfabs_(double x) { return x < 0 ? -x : x; }
constexpr double cexp_neg(double x) {
    double t = 1.0, s = 1.0;
    for (int i = 1; i < 20; ++i) { t *= (-x) / i; s += t; }
    return s;
}
constexpr double graw(int i) {
    double d = (double)(i - 32);
    return cexp_neg(d * d / 4225.0);
}
constexpr double gsum_() { double s = 0; for (int i = 0; i < 65; ++i) s += graw(i); return s; }
constexpr double GSUM_V = gsum_();
constexpr float gnv(int i) { return (float)(graw(i) / GSUM_V); }

struct WTab { float a[65]; };
constexpr WTab mkw(int sy) {
    WTab w{};
    for (int i = 0; i < 65; ++i) {
        double t = 13.0 - cfabs_((double)i - 16.0 * sy - 6.5);
        w.a[i] = (float)((graw(i) / GSUM_V) * t / 13.0);
    }
    return w;
}
constexpr WTab WGTBL[4] = { mkw(0), mkw(1), mkw(2), mkw(3) };
#define WGTG(SY, RR) (WGTBL[SY].a[RR])   // row gauss folded; compile-time literal
constexpr float G64F = gnv(64);

#define G4_(n) gnv(n), gnv(n+1), gnv(n+2), gnv(n+3)
__device__ __constant__ float d_gtab[65] = {
    G4_(0), G4_(4), G4_(8), G4_(12), G4_(16), G4_(20), G4_(24), G4_(28),
    G4_(32), G4_(36), G4_(40), G4_(44), G4_(48), G4_(52), G4_(56), G4_(60),
    gnv(64)
};

__device__ __forceinline__ float fast_atan2f(float y, float x) {
    float ax = fabsf(x), ay = fabsf(y);
    float mx = fmaxf(ax, ay);
    float mn = fminf(ax, ay);
    float a = mn * __builtin_amdgcn_rcpf(fmaxf(mx, 1e-30f));
    float s = a * a;
    float r = fmaf(s, fmaf(s, fmaf(s, fmaf(s, fmaf(s, -0.0117212f, 0.05265332f),
                    -0.11643287f), 0.19354346f), -0.33262347f), 0.99997726f) * a;
    r = (ay > ax) ? (1.57079637f - r) : r;
    r = (x < 0.0f) ? (3.14159274f - r) : r;
    return copysignf(r, y);
}

// DPP lane shift, VALU-only. Invalid lanes keep OLD (bound_ctrl=false):
// wave_shr:1 (0x138): lane i <- lane i-1, lane 0 keeps old[0]
// wave_shl:1 (0x130): lane i <- lane i+1, lane 63 keeps old[63]
template<int CTRL>
__device__ __forceinline__ float upd_dpp(float old, float src) {
    return __uint_as_float((unsigned)__builtin_amdgcn_update_dpp(
        (int)__float_as_uint(old), (int)__float_as_uint(src), CTRL, 0xF, 0xF, false));
}

__device__ __forceinline__ float rdlane_lit(float x, int l) {
    return __uint_as_float((unsigned)__builtin_amdgcn_readlane((int)__float_as_uint(x), l));
}

// wave64 sum via DPP + 4 readlane (no DS ops); result uniform.
__device__ __forceinline__ float wave_sum64(float v) {
    v += upd_dpp<0xB1>(v, v);    // quad_perm [1,0,3,2]
    v += upd_dpp<0x4E>(v, v);    // quad_perm [2,3,0,1]
    v += upd_dpp<0x141>(v, v);   // row_half_mirror
    v += upd_dpp<0x140>(v, v);   // row_mirror
    float a = rdlane_lit(v, 0)  + rdlane_lit(v, 16);
    float b = rdlane_lit(v, 32) + rdlane_lit(v, 48);
    return a + b;
}

#define FMA8(P, W)                                                        \
    P##0 = fmaf(s0, (W), P##0); P##1 = fmaf(s1, (W), P##1);               \
    P##2 = fmaf(s2, (W), P##2); P##3 = fmaf(s3, (W), P##3);               \
    P##4 = fmaf(s4, (W), P##4); P##5 = fmaf(s5, (W), P##5);               \
    P##6 = fmaf(s6, (W), P##6); P##7 = fmaf(s7, (W), P##7);

#define RDLC(RR) __uint_as_float((unsigned)__builtin_amdgcn_readlane((int)__float_as_uint(C64), (RR)))

// One pixel at (row RR, col lane) — R17-proven octant front end, gauss folded
// into weight literals. RR is a compile-time literal in every instantiation.
#define PIX(ARR, I, RR, ACCUM)                                            \
    {                                                                     \
        float c64r = ((RR) < 64) ? RDLC((RR) & 63) : c64top;              \
        float xc = ARR[I];                                                \
        float xl = upd_dpp<0x138>(xc, xc);                                \
        float xr = upd_dpp<0x130>(c64r, xc);                              \
        float dx = xr - xl;                                               \
        float dy = ARR[(I) + 1] - ARR[(I) - 1];                           \
        float ax_ = fabsf(dx), ay_ = fabsf(dy);                           \
        float mx = fmaxf(fmaxf(ax_, ay_), 1e-30f);                        \
        float mn = fminf(ax_, ay_);                                       \
        float t = mn * __builtin_amdgcn_rcpf(mx);                         \
        float ts = t * t;                                                 \
        float f = fmaf(ts, fmaf(ts, fmaf(ts, fmaf(ts, fmaf(ts,           \
                  -0.01492344f, 0.06703556f), -0.14824473f), 0.24642112f),\
                  -0.42350443f), 1.27321063f) * t;                        \
        float magw = sqrtf(fmaf(dx, dx, fmaf(dy, dy, 4e-10f))) * GCl;     \
        bool sdb = ay_ > ax_;                                             \
        bool sxb = dx < 0.0f;                                             \
        bool syb = dy < 0.0f;                                             \
        bool midb = sxb != syb;                                           \
        bool parb = sdb != midb;                                          \
        float wo1 = parb ? (1.0f - f) : f;                                \
        float q1 = wo1 * magw;                                            \
        float q0 = magw - q1;                                             \
        bool h0 = !syb && !midb && !parb;                                 \
        bool h1 = !syb && !midb &&  parb;                                 \
        bool h2 = !syb &&  midb && !parb;                                 \
        bool h3 = !syb &&  midb &&  parb;                                 \
        bool h4 =  syb && !midb && !parb;                                 \
        bool h5 =  syb && !midb &&  parb;                                 \
        bool h6 =  syb &&  midb && !parb;                                 \
        bool h7 =  syb &&  midb &&  parb;                                 \
        float s0 = h0 ? q0 : (h7 ? q1 : 0.0f);                            \
        float s1 = h1 ? q0 : (h0 ? q1 : 0.0f);                            \
        float s2 = h2 ? q0 : (h1 ? q1 : 0.0f);                            \
        float s3 = h3 ? q0 : (h2 ? q1 : 0.0f);                            \
        float s4 = h4 ? q0 : (h3 ? q1 : 0.0f);                            \
        float s5 = h5 ? q0 : (h4 ? q1 : 0.0f);                            \
        float s6 = h6 ? q0 : (h5 ? q1 : 0.0f);                            \
        float s7 = h7 ? q0 : (h6 ? q1 : 0.0f);                            \
        ACCUM                                                             \
    }

#define LOAD_RA(BASE)                                                     \
    _Pragma("unroll")                                                     \
    for (int i = 0; i < 18; ++i) {                                        \
        int rr = (BASE) + i; rr = (rr < 0) ? 0 : ((rr > 64) ? 64 : rr);   \
        RA[i] = src[rr * 520 + lane];                                     \
    }
#define LOAD_RB(BASE)                                                     \
    _Pragma("unroll")                                                     \
    for (int i = 0; i < 19; ++i) {                                        \
        int rr = (BASE) + i; rr = (rr < 0) ? 0 : ((rr > 64) ? 64 : rr);   \
        RB[i] = src[rr * 520 + lane];                                     \
    }
#define PIN_RA  _Pragma("unroll") for (int i = 0; i < 18; ++i) asm volatile("" : "+v"(RA[i]));
#define PIN_RB  _Pragma("unroll") for (int i = 0; i < 19; ++i) asm volatile("" : "+v"(RB[i]));

// One wave per patch, lane = column. R17-proven straight-line 4-phase
// double-buffered structure. waves_per_eu(1,2): max=2 residency trades the
// 3rd wave for a 128-VGPR budget so the scheduler can keep 2-3 independent
// pixel bodies in flight (the 85-VGPR budget fit only ~1.2 -> 22% duty).
__global__ __launch_bounds__(64)
__attribute__((amdgpu_waves_per_eu(1, 2)))
void sift_kernel(const float* __restrict__ in, float* __restrict__ out) {
    __shared__ float part[65 * PSTR];  // [column][sy*8 + a]
    __shared__ float c64buf[67];       // col-64 rows -1..65 (tail section only)

    const int lane = threadIdx.x;
    const int m  = blockIdx.x;
    const int bc = m >> 6;
    const int ij = m & 63;
    const float* src = in + (size_t)bc * (520 * 520) + (ij >> 3) * (65 * 520) + (ij & 7) * 65;

    // ---- staging: col-64 halo (LDS, tail use) + col-64 register column ----
    {
        int rr = lane - 1; rr = (rr < 0) ? 0 : rr;
        c64buf[lane] = src[rr * 520 + 64];
        if (lane < 3) {
            int r2 = 63 + lane; r2 = (r2 > 64) ? 64 : r2;
            c64buf[64 + lane] = src[r2 * 520 + 64];
        }
        if (lane < 32) part[64 * PSTR + lane] = 0.0f;
    }
    float C64    = src[lane * 520 + 64];  // lane r -> col64[row r], rows 0..63
    float c64top = src[64 * 520 + 64];    // col64[row 64] (uniform broadcast)
    float xl63   = src[lane * 520 + 63];  // col63[row=lane]
    float xl63b  = src[64 * 520 + 63];    // col63[row=64] (broadcast)

    // ---- row-buffer loads: phase A (rows -1..16) and phase B (rows 15..33) ----
    float RA[18], RB[19];
    LOAD_RA(-1)
    LOAD_RB(15)

    // ---- gaussian from compile-time table ----
    const float gl  = d_gtab[lane];      // gauss(col)
    const float g64 = G64F;              // literal
    const float GCl = 0.5f * gl;         // 0.5 grad scale folded

    const int cb = lane * PSTR;

    float A0=0,A1=0,A2=0,A3=0,A4=0,A5=0,A6=0,A7=0;   // window 0
    float B0=0,B1=0,B2=0,B3=0,B4=0,B5=0,B6=0,B7=0;   // window 1
    float C0=0,C1=0,C2=0,C3=0,C4=0,C5=0,C6=0,C7=0;   // window 2
    float F0=0,F1=0,F2=0,F3=0,F4=0,F5=0,F6=0,F7=0;   // window 3

    // ======= PHASE A: rows 0..15 (RA[i]=row i-1) =======
    PIN_RA
    #pragma unroll
    for (int r = 0; r < 10; ++r)   PIX(RA, r + 1, r, FMA8(A, WGTG(0, r)))
    #pragma unroll
    for (int r = 10; r < 16; ++r)  PIX(RA, r + 1, r, FMA8(A, WGTG(0, r)) FMA8(B, WGTG(1, r)))

    // refill RA with phase-C rows (31..48); drain RB for phase B
    LOAD_RA(31)
    PIN_RB
    // ======= PHASE B: rows 16..31 (RB[i]=row 15+i) =======
    #pragma unroll
    for (int r = 16; r < 20; ++r)  PIX(RB, r - 15, r, FMA8(A, WGTG(0, r)) FMA8(B, WGTG(1, r)))
    #pragma unroll
    for (int r = 20; r < 26; ++r)  PIX(RB, r - 15, r, FMA8(B, WGTG(1, r)))
    #pragma unroll
    for (int r = 26; r < 32; ++r)  PIX(RB, r - 15, r, FMA8(B, WGTG(1, r)) FMA8(C, WGTG(2, r)))
    // flush window 0
    part[cb + 0] = A0; part[cb + 1] = A1; part[cb + 2] = A2; part[cb + 3] = A3;
    part[cb + 4] = A4; part[cb + 5] = A5; part[cb + 6] = A6; part[cb + 7] = A7;

    // refill RB with phase-D rows (47..65); drain RA for phase C
    LOAD_RB(47)
    PIN_RA
    // ======= PHASE C: rows 32..47 (RA[i]=row 31+i) =======
    #pragma unroll
    for (int r = 32; r < 36; ++r)  PIX(RA, r - 31, r, FMA8(B, WGTG(1, r)) FMA8(C, WGTG(2, r)))
    #pragma unroll
    for (int r = 36; r < 42; ++r)  PIX(RA, r - 31, r, FMA8(C, WGTG(2, r)))
    #pragma unroll
    for (int r = 42; r < 48; ++r)  PIX(RA, r - 31, r, FMA8(C, WGTG(2, r)) FMA8(F, WGTG(3, r)))
    // flush window 1
    part[cb + 8] = B0; part[cb + 9] = B1; part[cb +10] = B2; part[cb +11] = B3;
    part[cb +12] = B4; part[cb +13] = B5; part[cb +14] = B6; part[cb +15] = B7;

    PIN_RB
    // ======= PHASE D: rows 48..64 (RB[i]=row 47+i) =======
    #pragma unroll
    for (int r = 48; r < 52; ++r)  PIX(RB, r - 47, r, FMA8(C, WGTG(2, r)) FMA8(F, WGTG(3, r)))
    #pragma unroll
    for (int r = 52; r < 65; ++r)  PIX(RB, r - 47, r, FMA8(F, WGTG(3, r)))
    // flush windows 2 and 3
    part[cb +16] = C0; part[cb +17] = C1; part[cb +18] = C2; part[cb +19] = C3;
    part[cb +20] = C4; part[cb +21] = C5; part[cb +22] = C6; part[cb +23] = C7;
    part[cb +24] = F0; part[cb +25] = F1; part[cb +26] = F2; part[cb +27] = F3;
    part[cb +28] = F4; part[cb +29] = F5; part[cb +30] = F6; part[cb +31] = F7;

    // ======= column 64: rows 0..63 (lane=row) + row 64 (lane 0) — proven tail =======
    {
        int r = lane;
        float xu  = c64buf[r];         // col64[r-1]
        float xcc = c64buf[r + 1];     // col64[r]
        float xd  = c64buf[r + 2];     // col64[r+1]
        float dx = xcc - xl63;         // right neighbor replicates to xcc
        float dy = xd - xu;
        float magw = sqrtf(fmaf(dx, dx, fmaf(dy, dy, 4e-10f))) * (gl * (0.5f * g64));
        float ang = fast_atan2f(dy, dx + 2e-10f);
        float o   = fmaf(ang, 1.27323954f, 8.0f);
        int bi = (int)o;
        float wo1 = o - (float)bi;
        int b0 = bi & 7;
        int b1 = (bi + 1) & 7;
        float q1 = wo1 * magw;
        float q0 = magw - q1;
        float* eb = &part[64 * PSTR];
        int syA = (r + 6) >> 4; if (syA > 3) syA = 3;
        float uA = (float)(r - 16 * syA + 6);
        float wA = (13.0f - fabsf(uA - 12.5f)) * (1.0f / 13.0f);
        atomicAdd(eb + syA * 8 + b0, q0 * wA);
        atomicAdd(eb + syA * 8 + b1, q1 * wA);
        int syB = syA - 1;
        if (syB >= 0) {
            float uB = (float)(r - 16 * syB + 6);
            float wB = (13.0f - fabsf(uB - 12.5f)) * (1.0f / 13.0f);
            if (wB > 0.0f) {
                atomicAdd(eb + syB * 8 + b0, q0 * wB);
                atomicAdd(eb + syB * 8 + b1, q1 * wB);
            }
        }
        if (lane == 0) {   // pixel (64,64): window 3 only
            float xu2  = c64buf[64];
            float xc2  = c64buf[65];
            float xd2  = c64buf[66];
            float dx2 = xc2 - xl63b;
            float dy2 = xd2 - xu2;
            float mg = sqrtf(fmaf(dx2, dx2, fmaf(dy2, dy2, 4e-10f))) * (g64 * (0.5f * g64));
            float an = fast_atan2f(dy2, dx2 + 2e-10f);
            float o2 = fmaf(an, 1.27323954f, 8.0f);
            int bi2 = (int)o2;
            float w1 = o2 - (float)bi2;
            int c0 = bi2 & 7;
            int c1 = (bi2 + 1) & 7;
            float p1 = w1 * mg;
            float p0 = mg - p1;
            const float w64 = 3.5f * (1.0f / 13.0f);
            atomicAdd(eb + 3 * 8 + c0, p0 * w64);
            atomicAdd(eb + 3 * 8 + c1, p1 * w64);
        }
    }

    // ======= column pooling + double-normalize (DPP reduce) + store =======
    {
        float v0, v1;
        #pragma unroll
        for (int h = 0; h < 2; ++h) {
            int o  = lane + h * 64;
            int a  = o >> 4;
            int sy = (o >> 2) & 3;
            int sx = o & 3;
            float s = 0.0f;
            #pragma unroll 2
            for (int k = 0; k < 26; ++k) {
                int c = sx * 16 - 6 + k;
                if ((unsigned)c <= 64u) {
                    float wc = (13.0f - fabsf((float)k - 12.5f)) * (1.0f / 13.0f);
                    s = fmaf(wc, part[c * PSTR + sy * 8 + a], s);
                }
            }
            if (h == 0) v0 = s; else v1 = s;
        }
        float ss = wave_sum64(v0 * v0 + v1 * v1);
        float sc = 1.0f / fmaxf(sqrtf(ss), 1e-12f);
        v0 = fminf(fmaxf(v0 * sc, 0.0f), 0.2f);
        v1 = fminf(fmaxf(v1 * sc, 0.0f), 0.2f);
        ss = wave_sum64(v0 * v0 + v1 * v1);
        sc = 1.0f / fmaxf(sqrtf(ss), 1e-12f);
        out[(size_t)m * 128 + lane]      = v0 * sc;
        out[(size_t)m * 128 + lane + 64] = v1 * sc;
    }
}

extern "C" void kernel_launch(void* const* d_in, const int* in_sizes, int n_in,
                              void* d_out, int out_size, void* d_ws, size_t ws_size,
                              hipStream_t stream) {
    const float* in = (const float*)d_in[0];
    float* out = (float*)d_out;
    sift_kernel<<<3072, 64, 0, stream>>>(in, out);
}

// Round 23
// 39.833 us; speedup vs baseline: 1.1244x; 1.1244x over previous
//
#include <hip/hip_runtime.h>
#include <math.h>

#define PSTR 33   // part[] col stride: 33 mod 32 = 1 -> benign 2-way bank aliasing

// ======== compile-time gaussian (sigma=65/sqrt(2), normalized over 65) ========
constexpr double cfabs_(double x) { return x < 0 ? -x : x; }
constexpr double cexp_neg(double x) {   // exp(-x), x in [0, 0.25]
    double t = 1.0, s = 1.0;
    for (int i = 1; i < 20; ++i) { t *= (-x) / i; s += t; }
    return s;
}
constexpr double graw(int i) {
    double d = (double)(i - 32);
    return cexp_neg(d * d / 4225.0);
}
constexpr double gsum_() { double s = 0; for (int i = 0; i < 65; ++i) s += graw(i); return s; }
constexpr double GSUM_V = gsum_();
constexpr float gnv(int i) { return (float)(graw(i) / GSUM_V); }

struct WTab { float a[65]; };
constexpr WTab mkw(int sy) {
    WTab w{};
    for (int i = 0; i < 65; ++i) {
        double t = 13.0 - cfabs_((double)i - 16.0 * sy - 6.5);
        w.a[i] = (float)((graw(i) / GSUM_V) * t / 13.0);
    }
    return w;
}
constexpr WTab WGTBL[4] = { mkw(0), mkw(1), mkw(2), mkw(3) };
// weight with gn(row) folded; SY and RR are compile-time after unrolling
#define WGTG(SY, RR) (WGTBL[SY].a[RR])
constexpr float G64F = gnv(64);

#define G4_(n) gnv(n), gnv(n+1), gnv(n+2), gnv(n+3)
__device__ __constant__ float d_gtab[65] = {
    G4_(0), G4_(4), G4_(8), G4_(12), G4_(16), G4_(20), G4_(24), G4_(28),
    G4_(32), G4_(36), G4_(40), G4_(44), G4_(48), G4_(52), G4_(56), G4_(60),
    gnv(64)
};

__device__ __forceinline__ float fast_atan2f(float y, float x) {
    float ax = fabsf(x), ay = fabsf(y);
    float mx = fmaxf(ax, ay);
    float mn = fminf(ax, ay);
    float a = mn * __builtin_amdgcn_rcpf(fmaxf(mx, 1e-30f));
    float s = a * a;
    float r = fmaf(s, fmaf(s, fmaf(s, fmaf(s, fmaf(s, -0.0117212f, 0.05265332f),
                    -0.11643287f), 0.19354346f), -0.33262347f), 0.99997726f) * a;
    r = (ay > ax) ? (1.57079637f - r) : r;
    r = (x < 0.0f) ? (3.14159274f - r) : r;
    return copysignf(r, y);
}

// DPP lane shift, VALU-only. Invalid lanes keep OLD (bound_ctrl=false):
// wave_shr:1 (0x138): lane i <- lane i-1, lane 0 keeps old[0]
// wave_shl:1 (0x130): lane i <- lane i+1, lane 63 keeps old[63]
template<int CTRL>
__device__ __forceinline__ float upd_dpp(float old, float src) {
    return __uint_as_float((unsigned)__builtin_amdgcn_update_dpp(
        (int)__float_as_uint(old), (int)__float_as_uint(src), CTRL, 0xF, 0xF, false));
}

__device__ __forceinline__ float rdlane_lit(float x, int l) {   // compile-time lane
    return __uint_as_float((unsigned)__builtin_amdgcn_readlane((int)__float_as_uint(x), l));
}

// wave64 sum via DPP (quad_perm xor1/xor2, half_mirror, mirror) + 4 readlane.
// No DS ops; result uniform across lanes.
__device__ __forceinline__ float wave_sum64(float v) {
    v += upd_dpp<0xB1>(v, v);    // quad_perm [1,0,3,2]
    v += upd_dpp<0x4E>(v, v);    // quad_perm [2,3,0,1]
    v += upd_dpp<0x141>(v, v);   // row_half_mirror
    v += upd_dpp<0x140>(v, v);   // row_mirror -> each row of 16 fully reduced
    float a = rdlane_lit(v, 0)  + rdlane_lit(v, 16);
    float b = rdlane_lit(v, 32) + rdlane_lit(v, 48);
    return a + b;
}

#define FMA8(P, W)                                                        \
    P##0 = fmaf(s0, (W), P##0); P##1 = fmaf(s1, (W), P##1);               \
    P##2 = fmaf(s2, (W), P##2); P##3 = fmaf(s3, (W), P##3);               \
    P##4 = fmaf(s4, (W), P##4); P##5 = fmaf(s5, (W), P##5);               \
    P##6 = fmaf(s6, (W), P##6); P##7 = fmaf(s7, (W), P##7);

// col64[row] from per-lane register C64 via readlane (compile-time lane index)
#define RDLC(RR) __uint_as_float((unsigned)__builtin_amdgcn_readlane((int)__float_as_uint(C64), (RR)))

// One pixel at (row RR, col lane). Octant binning (R14-proven); gauss(row) is
// folded into the FMA weight literals, so no per-pixel readlane/mul for it.
#define PIX(ARR, I, RR, ACCUM)                                            \
    {                                                                     \
        float c64r = ((RR) < 64) ? RDLC((RR) & 63) : c64top;              \
        float xc = ARR[I];                                                \
        float xl = upd_dpp<0x138>(xc, xc);                                \
        float xr = upd_dpp<0x130>(c64r, xc);                              \
        float dx = xr - xl;                                               \
        float dy = ARR[(I) + 1] - ARR[(I) - 1];                           \
        float ax_ = fabsf(dx), ay_ = fabsf(dy);                           \
        float mx = fmaxf(fmaxf(ax_, ay_), 1e-30f);                        \
        float mn = fminf(ax_, ay_);                                       \
        float t = mn * __builtin_amdgcn_rcpf(mx);                         \
        float ts = t * t;                                                 \
        float f = fmaf(ts, fmaf(ts, fmaf(ts, fmaf(ts, fmaf(ts,           \
                  -0.01492344f, 0.06703556f), -0.14824473f), 0.24642112f),\
                  -0.42350443f), 1.27321063f) * t;                        \
        float magw = sqrtf(fmaf(dx, dx, fmaf(dy, dy, 4e-10f))) * GCl;     \
        bool sdb = ay_ > ax_;                                             \
        bool sxb = dx < 0.0f;                                             \
        bool syb = dy < 0.0f;                                             \
        bool midb = sxb != syb;                                           \
        bool parb = sdb != midb;                                          \
        float wo1 = parb ? (1.0f - f) : f;                                \
        float q1 = wo1 * magw;                                            \
        float q0 = magw - q1;                                             \
        bool h0 = !syb && !midb && !parb;                                 \
        bool h1 = !syb && !midb &&  parb;                                 \
        bool h2 = !syb &&  midb && !parb;                                 \
        bool h3 = !syb &&  midb &&  parb;                                 \
        bool h4 =  syb && !midb && !parb;                                 \
        bool h5 =  syb && !midb &&  parb;                                 \
        bool h6 =  syb &&  midb && !parb;                                 \
        bool h7 =  syb &&  midb &&  parb;                                 \
        float s0 = h0 ? q0 : (h7 ? q1 : 0.0f);                            \
        float s1 = h1 ? q0 : (h0 ? q1 : 0.0f);                            \
        float s2 = h2 ? q0 : (h1 ? q1 : 0.0f);                            \
        float s3 = h3 ? q0 : (h2 ? q1 : 0.0f);                            \
        float s4 = h4 ? q0 : (h3 ? q1 : 0.0f);                            \
        float s5 = h5 ? q0 : (h4 ? q1 : 0.0f);                            \
        float s6 = h6 ? q0 : (h5 ? q1 : 0.0f);                            \
        float s7 = h7 ? q0 : (h6 ? q1 : 0.0f);                            \
        ACCUM                                                             \
    }

#define LOAD_RA(BASE)                                                     \
    _Pragma("unroll")                                                     \
    for (int i = 0; i < 18; ++i) {                                        \
        int rr = (BASE) + i; rr = (rr < 0) ? 0 : ((rr > 64) ? 64 : rr);   \
        RA[i] = src[rr * 520 + lane];                                     \
    }
#define LOAD_RB(BASE)                                                     \
    _Pragma("unroll")                                                     \
    for (int i = 0; i < 19; ++i) {                                        \
        int rr = (BASE) + i; rr = (rr < 0) ? 0 : ((rr > 64) ? 64 : rr);   \
        RB[i] = src[rr * 520 + lane];                                     \
    }
#define PIN_RA  _Pragma("unroll") for (int i = 0; i < 18; ++i) asm volatile("" : "+v"(RA[i]));
#define PIN_RB  _Pragma("unroll") for (int i = 0; i < 19; ++i) asm volatile("" : "+v"(RB[i]));

// One wave per patch, lane = column. Straight-line 4-phase double-buffered
// structure (R14-proven). Gauss folded into compile-time weight literals.
// R17 configuration: best measured (40.2 us, absmax 4.88e-4, VGPR 68).
__global__ __launch_bounds__(64)
__attribute__((amdgpu_waves_per_eu(2, 3)))
void sift_kernel(const float* __restrict__ in, float* __restrict__ out) {
    __shared__ float part[65 * PSTR];  // [column][sy*8 + a]
    __shared__ float c64buf[67];       // col-64 rows -1..65 (tail section only)

    const int lane = threadIdx.x;
    const int m  = blockIdx.x;
    const int bc = m >> 6;
    const int ij = m & 63;
    const float* src = in + (size_t)bc * (520 * 520) + (ij >> 3) * (65 * 520) + (ij & 7) * 65;

    // ---- staging: col-64 halo (LDS, tail use) + col-64 register column ----
    {
        int rr = lane - 1; rr = (rr < 0) ? 0 : rr;
        c64buf[lane] = src[rr * 520 + 64];
        if (lane < 3) {
            int r2 = 63 + lane; r2 = (r2 > 64) ? 64 : r2;
            c64buf[64 + lane] = src[r2 * 520 + 64];
        }
        if (lane < 32) part[64 * PSTR + lane] = 0.0f;
    }
    float C64    = src[lane * 520 + 64];  // lane r -> col64[row r], rows 0..63
    float c64top = src[64 * 520 + 64];    // col64[row 64] (uniform broadcast)
    float xl63   = src[lane * 520 + 63];  // col63[row=lane]
    float xl63b  = src[64 * 520 + 63];    // col63[row=64] (broadcast)

    // ---- row-buffer loads: phase A (rows -1..16) and phase B (rows 15..33) ----
    float RA[18], RB[19];
    LOAD_RA(-1)
    LOAD_RB(15)

    // ---- gaussian from compile-time table ----
    const float gl  = d_gtab[lane];      // gauss(col)
    const float g64 = G64F;              // literal
    const float GCl = 0.5f * gl;         // 0.5 grad scale folded

    const int cb = lane * PSTR;

    float A0=0,A1=0,A2=0,A3=0,A4=0,A5=0,A6=0,A7=0;   // window 0
    float B0=0,B1=0,B2=0,B3=0,B4=0,B5=0,B6=0,B7=0;   // window 1
    float C0=0,C1=0,C2=0,C3=0,C4=0,C5=0,C6=0,C7=0;   // window 2
    float F0=0,F1=0,F2=0,F3=0,F4=0,F5=0,F6=0,F7=0;   // window 3

    // ======= PHASE A: rows 0..15 (RA[i]=row i-1) =======
    PIN_RA
    #pragma unroll
    for (int r = 0; r < 10; ++r)   PIX(RA, r + 1, r, FMA8(A, WGTG(0, r)))
    #pragma unroll
    for (int r = 10; r < 16; ++r)  PIX(RA, r + 1, r, FMA8(A, WGTG(0, r)) FMA8(B, WGTG(1, r)))

    // refill RA with phase-C rows (31..48); drain RB for phase B
    LOAD_RA(31)
    PIN_RB
    // ======= PHASE B: rows 16..31 (RB[i]=row 15+i) =======
    #pragma unroll
    for (int r = 16; r < 20; ++r)  PIX(RB, r - 15, r, FMA8(A, WGTG(0, r)) FMA8(B, WGTG(1, r)))
    #pragma unroll
    for (int r = 20; r < 26; ++r)  PIX(RB, r - 15, r, FMA8(B, WGTG(1, r)))
    #pragma unroll
    for (int r = 26; r < 32; ++r)  PIX(RB, r - 15, r, FMA8(B, WGTG(1, r)) FMA8(C, WGTG(2, r)))
    // flush window 0
    part[cb + 0] = A0; part[cb + 1] = A1; part[cb + 2] = A2; part[cb + 3] = A3;
    part[cb + 4] = A4; part[cb + 5] = A5; part[cb + 6] = A6; part[cb + 7] = A7;

    // refill RB with phase-D rows (47..65); drain RA for phase C
    LOAD_RB(47)
    PIN_RA
    // ======= PHASE C: rows 32..47 (RA[i]=row 31+i) =======
    #pragma unroll
    for (int r = 32; r < 36; ++r)  PIX(RA, r - 31, r, FMA8(B, WGTG(1, r)) FMA8(C, WGTG(2, r)))
    #pragma unroll
    for (int r = 36; r < 42; ++r)  PIX(RA, r - 31, r, FMA8(C, WGTG(2, r)))
    #pragma unroll
    for (int r = 42; r < 48; ++r)  PIX(RA, r - 31, r, FMA8(C, WGTG(2, r)) FMA8(F, WGTG(3, r)))
    // flush window 1
    part[cb + 8] = B0; part[cb + 9] = B1; part[cb +10] = B2; part[cb +11] = B3;
    part[cb +12] = B4; part[cb +13] = B5; part[cb +14] = B6; part[cb +15] = B7;

    PIN_RB
    // ======= PHASE D: rows 48..64 (RB[i]=row 47+i) =======
    #pragma unroll
    for (int r = 48; r < 52; ++r)  PIX(RB, r - 47, r, FMA8(C, WGTG(2, r)) FMA8(F, WGTG(3, r)))
    #pragma unroll
    for (int r = 52; r < 65; ++r)  PIX(RB, r - 47, r, FMA8(F, WGTG(3, r)))
    // flush windows 2 and 3
    part[cb +16] = C0; part[cb +17] = C1; part[cb +18] = C2; part[cb +19] = C3;
    part[cb +20] = C4; part[cb +21] = C5; part[cb +22] = C6; part[cb +23] = C7;
    part[cb +24] = F0; part[cb +25] = F1; part[cb +26] = F2; part[cb +27] = F3;
    part[cb +28] = F4; part[cb +29] = F5; part[cb +30] = F6; part[cb +31] = F7;

    // ======= column 64: rows 0..63 (lane=row) + row 64 (lane 0) — proven tail =======
    {
        int r = lane;
        float xu  = c64buf[r];         // col64[r-1]
        float xcc = c64buf[r + 1];     // col64[r]
        float xd  = c64buf[r + 2];     // col64[r+1]
        float dx = xcc - xl63;         // right neighbor replicates to xcc
        float dy = xd - xu;
        float magw = sqrtf(fmaf(dx, dx, fmaf(dy, dy, 4e-10f))) * (gl * (0.5f * g64));
        float ang = fast_atan2f(dy, dx + 2e-10f);
        float o   = fmaf(ang, 1.27323954f, 8.0f);
        int bi = (int)o;
        float wo1 = o - (float)bi;
        int b0 = bi & 7;
        int b1 = (bi + 1) & 7;
        float q1 = wo1 * magw;
        float q0 = magw - q1;
        float* eb = &part[64 * PSTR];
        int syA = (r + 6) >> 4; if (syA > 3) syA = 3;
        float uA = (float)(r - 16 * syA + 6);
        float wA = (13.0f - fabsf(uA - 12.5f)) * (1.0f / 13.0f);
        atomicAdd(eb + syA * 8 + b0, q0 * wA);
        atomicAdd(eb + syA * 8 + b1, q1 * wA);
        int syB = syA - 1;
        if (syB >= 0) {
            float uB = (float)(r - 16 * syB + 6);
            float wB = (13.0f - fabsf(uB - 12.5f)) * (1.0f / 13.0f);
            if (wB > 0.0f) {
                atomicAdd(eb + syB * 8 + b0, q0 * wB);
                atomicAdd(eb + syB * 8 + b1, q1 * wB);
            }
        }
        if (lane == 0) {   // pixel (64,64): window 3 only
            float xu2  = c64buf[64];
            float xc2  = c64buf[65];
            float xd2  = c64buf[66];
            float dx2 = xc2 - xl63b;
            float dy2 = xd2 - xu2;
            float mg = sqrtf(fmaf(dx2, dx2, fmaf(dy2, dy2, 4e-10f))) * (g64 * (0.5f * g64));
            float an = fast_atan2f(dy2, dx2 + 2e-10f);
            float o2 = fmaf(an, 1.27323954f, 8.0f);
            int bi2 = (int)o2;
            float w1 = o2 - (float)bi2;
            int c0 = bi2 & 7;
            int c1 = (bi2 + 1) & 7;
            float p1 = w1 * mg;
            float p0 = mg - p1;
            const float w64 = 3.5f * (1.0f / 13.0f);
            atomicAdd(eb + 3 * 8 + c0, p0 * w64);
            atomicAdd(eb + 3 * 8 + c1, p1 * w64);
        }
    }

    // ======= column pooling + double-normalize (DPP reduce) + store =======
    {
        float v0, v1;
        #pragma unroll
        for (int h = 0; h < 2; ++h) {
            int o  = lane + h * 64;
            int a  = o >> 4;
            int sy = (o >> 2) & 3;
            int sx = o & 3;
            float s = 0.0f;
            #pragma unroll 2
            for (int k = 0; k < 26; ++k) {
                int c = sx * 16 - 6 + k;
                if ((unsigned)c <= 64u) {
                    float wc = (13.0f - fabsf((float)k - 12.5f)) * (1.0f / 13.0f);
                    s = fmaf(wc, part[c * PSTR + sy * 8 + a], s);
                }
            }
            if (h == 0) v0 = s; else v1 = s;
        }
        float ss = wave_sum64(v0 * v0 + v1 * v1);
        float sc = 1.0f / fmaxf(sqrtf(ss), 1e-12f);
        v0 = fminf(fmaxf(v0 * sc, 0.0f), 0.2f);
        v1 = fminf(fmaxf(v1 * sc, 0.0f), 0.2f);
        ss = wave_sum64(v0 * v0 + v1 * v1);
        sc = 1.0f / fmaxf(sqrtf(ss), 1e-12f);
        out[(size_t)m * 128 + lane]      = v0 * sc;
        out[(size_t)m * 128 + lane + 64] = v1 * sc;
    }
}

extern "C" void kernel_launch(void* const* d_in, const int* in_sizes, int n_in,
                              void* d_out, int out_size, void* d_ws, size_t ws_size,
                              hipStream_t stream) {
    const float* in = (const float*)d_in[0];
    float* out = (float*)d_out;
    sift_kernel<<<3072, 64, 0, stream>>>(in, out);
}